// Round 1
// baseline (30929.935 us; speedup 1.0000x reference)
//
#include <hip/hip_runtime.h>
#include <math.h>

// Problem constants
#define B_ 32
#define T_ 512
#define N_ 512
#define D_ 4
#define H_ 2048
#define C_ 128

// ---------------- helpers ----------------
__device__ __forceinline__ float bflo(unsigned p) { return __uint_as_float(p << 16); }
__device__ __forceinline__ float bfhi(unsigned p) { return __uint_as_float(p & 0xffff0000u); }
__device__ __forceinline__ unsigned f2bf(float x) {
    unsigned u = __float_as_uint(x);
    return (u + 0x7fffu + ((u >> 16) & 1u)) >> 16;
}

// ---------------- generic f32 GEMM: C[M,N] = A[M,K] @ B[K,N] + bias[N] ----------------
// 128x128 tile, BK=16, 256 threads, 8x8 microtile. Requires M%128==0, N%128==0, K%16==0.
__global__ __launch_bounds__(256) void gemm_f32(
    const float* __restrict__ A, const float* __restrict__ Bm,
    const float* __restrict__ bias, float* __restrict__ C,
    int M, int N, int K) {
    __shared__ float As[16][132];
    __shared__ float Bs[16][132];
    const int tid = threadIdx.x;
    const int tx = tid & 15, ty = tid >> 4;
    const int bx = blockIdx.x, by = blockIdx.y;
    float acc[8][8];
#pragma unroll
    for (int i = 0; i < 8; ++i)
#pragma unroll
        for (int j = 0; j < 8; ++j) acc[i][j] = 0.f;
    const size_t Abase = (size_t)(by * 128) * K;
    for (int k0 = 0; k0 < K; k0 += 16) {
#pragma unroll
        for (int it = 0; it < 8; ++it) {
            int flat = it * 256 + tid;
            int r = flat >> 4, c = flat & 15;
            As[c][r] = A[Abase + (size_t)r * K + (k0 + c)];
        }
#pragma unroll
        for (int it = 0; it < 8; ++it) {
            int flat = it * 256 + tid;
            int r = flat >> 7, c = flat & 127;
            Bs[r][c] = Bm[(size_t)(k0 + r) * N + bx * 128 + c];
        }
        __syncthreads();
#pragma unroll
        for (int kk = 0; kk < 16; ++kk) {
            float a[8], bv[8];
            *(float4*)&a[0] = *(const float4*)&As[kk][ty * 8];
            *(float4*)&a[4] = *(const float4*)&As[kk][ty * 8 + 4];
            *(float4*)&bv[0] = *(const float4*)&Bs[kk][tx * 8];
            *(float4*)&bv[4] = *(const float4*)&Bs[kk][tx * 8 + 4];
#pragma unroll
            for (int i = 0; i < 8; ++i)
#pragma unroll
                for (int j = 0; j < 8; ++j)
                    acc[i][j] = fmaf(a[i], bv[j], acc[i][j]);
        }
        __syncthreads();
    }
#pragma unroll
    for (int i = 0; i < 8; ++i) {
        size_t row = (size_t)(by * 128 + ty * 8 + i);
#pragma unroll
        for (int j = 0; j < 8; ++j) {
            int col = bx * 128 + tx * 8 + j;
            C[row * (size_t)N + col] = acc[i][j] + bias[col];
        }
    }
}

// ---------------- LayerNorm + LeakyReLU over rows of H=2048, in place ----------------
__device__ __forceinline__ float block_sum256(float v, float* red) {
#pragma unroll
    for (int o = 32; o > 0; o >>= 1) v += __shfl_down(v, o, 64);
    int w = threadIdx.x >> 6;
    if ((threadIdx.x & 63) == 0) red[w] = v;
    __syncthreads();
    float r = red[0] + red[1] + red[2] + red[3];
    __syncthreads();
    return r;
}

__global__ __launch_bounds__(256) void ln_leaky_kernel(
    float* __restrict__ Z, const float* __restrict__ gam, const float* __restrict__ bet) {
    __shared__ float red[4];
    const size_t row = blockIdx.x;
    float* zr = Z + row * H_;
    const int tid = threadIdx.x;
    float v[8];
    float s = 0.f;
#pragma unroll
    for (int i = 0; i < 8; ++i) { v[i] = zr[tid + i * 256]; s += v[i]; }
    s = block_sum256(s, red);
    float mu = s * (1.f / H_);
    float q = 0.f;
#pragma unroll
    for (int i = 0; i < 8; ++i) { float d = v[i] - mu; q += d * d; }
    q = block_sum256(q, red);
    float rs = rsqrtf(q * (1.f / H_) + 1e-5f);
#pragma unroll
    for (int i = 0; i < 8; ++i) {
        int c = tid + i * 256;
        float y = (v[i] - mu) * rs * gam[c] + bet[c];
        zr[c] = y > 0.f ? y : 0.1f * y;
    }
}

// ---------------- persistent theta-scan kernel ----------------
// 256 blocks x 256 threads, 1 block/CU (LDS 115840B), custom grid barrier.
__device__ __forceinline__ void grid_barrier(unsigned* cnt, unsigned* gen, unsigned nb) {
    __syncthreads();
    if (threadIdx.x == 0) {
        __threadfence();
        unsigned g = __hip_atomic_load(gen, __ATOMIC_RELAXED, __HIP_MEMORY_SCOPE_AGENT);
        unsigned a = __hip_atomic_fetch_add(cnt, 1u, __ATOMIC_ACQ_REL, __HIP_MEMORY_SCOPE_AGENT);
        if (a == nb - 1u) {
            __hip_atomic_store(cnt, 0u, __ATOMIC_RELAXED, __HIP_MEMORY_SCOPE_AGENT);
            __hip_atomic_fetch_add(gen, 1u, __ATOMIC_RELEASE, __HIP_MEMORY_SCOPE_AGENT);
        } else {
            unsigned spins = 0;
            while (__hip_atomic_load(gen, __ATOMIC_RELAXED, __HIP_MEMORY_SCOPE_AGENT) == g) {
                __builtin_amdgcn_s_sleep(2);
                if (++spins > (1u << 27)) break;  // deadlock -> wrong answer, not hang
            }
        }
        __threadfence();
    }
    __syncthreads();
}

#define SCAN_LDS_BYTES 115840

__global__ __launch_bounds__(256, 1) void scan_kernel(
    const float* __restrict__ sc, const float* __restrict__ gamma,
    const float* __restrict__ omega, const float* __restrict__ Wm,
    const float* __restrict__ bm, float* __restrict__ feat,
    unsigned* __restrict__ stct,   // [2][512*128] packed bf16 (hi=cos, lo=sin), [j][bd]
    float* __restrict__ g_ring,    // [4][B_*N_]
    float* __restrict__ mh_ring,   // [4][B_*N_]
    unsigned* __restrict__ bar) {
    extern __shared__ char smem[];
    float* sc_lds = (float*)smem;                              // [32][516] f32
    unsigned* stct_lds = (unsigned*)(smem + 66048);            // [8][516]  u32
    unsigned short* g_lds = (unsigned short*)(smem + 82560);   // [32][520] bf16
    const int tid = threadIdx.x;
    const int ig = blockIdx.x >> 4, bg = blockIdx.x & 15;
    const int i_loc = tid >> 3, bd_loc = tid & 7;
    const int i = ig * 32 + i_loc;
    const int bd = (bg << 3) + bd_loc;
    const int b = bd >> 2, d = bd & 3;
    const bool isB = blockIdx.x < 64;            // blocks doing the mask GEMM
    const int Bb = tid >> 3;                     // 0..31
    const int Bn = (blockIdx.x << 3) + (tid & 7);
    unsigned* cnt = bar;
    unsigned* gen = bar + 1;

    // persistent sc tile: rows [ig*32, ig*32+32)
    for (int it = 0; it < 64; ++it) {
        int flat = it * 256 + tid;
        int r = flat >> 9, c = flat & 511;
        sc_lds[r * 516 + c] = sc[(size_t)(ig * 32 + r) * 512 + c];
    }
    const float omega_v = omega[i * 4 + d];
    const float bmask_v = isB ? bm[Bn] : 0.f;
    const float KdN = 1.0f / 512.0f;
    float theta = 0.f;
    float s_prev = 0.f, c_prev = 1.f;  // sin/cos of carried theta

    for (int t = 0; t < T_; ++t) {
        // -------- staging (reads synced at end of previous step) --------
        if (t > 0) {
            const unsigned* src = stct + (size_t)(t & 1) * 65536;
#pragma unroll
            for (int it = 0; it < 16; ++it) {
                int flat = it * 256 + tid;
                stct_lds[(flat & 7) * 516 + (flat >> 3)] =
                    src[(size_t)(flat >> 3) * 128 + (bg << 3) + (flat & 7)];
            }
            if (isB) {
                const float* gs = g_ring + (size_t)((t - 1) & 3) * (B_ * N_);
#pragma unroll
                for (int it = 0; it < 64; ++it) {
                    int flat = it * 256 + tid;
                    g_lds[(flat >> 9) * 520 + (flat & 511)] = (unsigned short)f2bf(gs[flat]);
                }
            }
        }
        __syncthreads();

        // -------- B work: mask_h for step t+1 (g from meanTheta_{t-1}) --------
        if (isB && t > 0) {
            float acc = 0.f;
            const unsigned short* gr = g_lds + Bb * 520;
#pragma unroll 4
            for (int m = 0; m < 512; ++m)
                acc = fmaf(__uint_as_float((unsigned)gr[m] << 16), Wm[(size_t)m * 512 + Bn], acc);
            float mh = 1.f / (1.f + expf(-(acc + bmask_v)));
            mh_ring[(size_t)((t + 1) & 3) * (B_ * N_) + Bb * 512 + Bn] = mh;
        }

        // -------- A work: coupling dot + theta update --------
        float Sst = 0.f, Sct = 0.f;
        if (t > 0) {
            const float* scrow = sc_lds + i_loc * 516;
            const unsigned* prow = stct_lds + bd_loc * 516;
#pragma unroll 2
            for (int j = 0; j < 512; j += 4) {
                float4 s4 = *(const float4*)(scrow + j);
                uint4 p4 = *(const uint4*)(prow + j);
                Sst = fmaf(s4.x, bflo(p4.x), Sst); Sct = fmaf(s4.x, bfhi(p4.x), Sct);
                Sst = fmaf(s4.y, bflo(p4.y), Sst); Sct = fmaf(s4.y, bfhi(p4.y), Sct);
                Sst = fmaf(s4.z, bflo(p4.z), Sst); Sct = fmaf(s4.z, bfhi(p4.z), Sct);
                Sst = fmaf(s4.w, bflo(p4.w), Sst); Sct = fmaf(s4.w, bfhi(p4.w), Sct);
            }
        }
        float coup = c_prev * Sst - s_prev * Sct;
        float gamma_v = gamma[(size_t)(b * T_ + t) * 512 + i];
        theta += 0.1f * (omega_v + gamma_v + KdN * coup);
        sincosf(theta, &s_prev, &c_prev);  // now sin/cos of theta_new
        stct[(size_t)((t + 1) & 1) * 65536 + i * 128 + bd] = (f2bf(c_prev) << 16) | f2bf(s_prev);
        float msum = theta;
        msum += __shfl_xor(msum, 1, 64);
        msum += __shfl_xor(msum, 2, 64);
        if (d == 0)
            g_ring[(size_t)(t & 3) * (B_ * N_) + b * 512 + i] = 0.5f + 0.5f * sinf(msum * 0.25f);

        // -------- bootstrap at t==0: compute mask_h for steps 0,1,2 --------
        if (t == 0) {
            grid_barrier(cnt, gen, 256);
            if (isB) {
                float acc = 0.f;
                for (int m = 0; m < 512; ++m)
                    acc = fmaf(g_ring[Bb * 512 + m], Wm[(size_t)m * 512 + Bn], acc);
                float mh = 1.f / (1.f + expf(-(acc + bmask_v)));
                mh_ring[Bb * 512 + Bn] = mh;
                mh_ring[(B_ * N_) + Bb * 512 + Bn] = mh;
                mh_ring[2 * (B_ * N_) + Bb * 512 + Bn] = mh;
            }
            grid_barrier(cnt, gen, 256);
        }

        // -------- feat_t = sin(theta_new) * g_t * mask_h_t --------
        int dslot = (t >= 2) ? ((t - 2) & 3) : 0;
        float gv = g_ring[(size_t)dslot * (B_ * N_) + b * 512 + i];
        float mhv = mh_ring[(size_t)(t & 3) * (B_ * N_) + b * 512 + i];
        feat[(size_t)(b * T_ + t) * 2048 + i * 4 + d] = s_prev * gv * mhv;

        grid_barrier(cnt, gen, 256);
    }
}

// ---------------- LIF membrane scan: cur -> spike, in place on [B,T,H] ----------------
__global__ __launch_bounds__(256) void mem_scan_kernel(float* __restrict__ io) {
    int tid = blockIdx.x * 256 + threadIdx.x;  // 65536 = B*H
    int h = tid & (H_ - 1), b = tid >> 11;
    float mem = 0.f;
    float* base = io + (size_t)b * T_ * H_ + h;
    for (int t = 0; t < T_; ++t) {
        float cur = base[(size_t)t * H_];
        mem = 0.5f * mem + cur;
        float sp = 1.f / (1.f + expf(-4.f * (mem - 1.f)));
        mem -= sp;
        base[(size_t)t * H_] = sp;
    }
}

// ---------------- conv1d(k=5,pad=2) over T + log_softmax over C ----------------
// snn: [B*T, 128] rows (b*T+t). out0: [B,128,512].
__global__ __launch_bounds__(128) void conv_lsm_kernel(
    const float* __restrict__ snn, const float* __restrict__ Wc,
    const float* __restrict__ bc, float* __restrict__ out0) {
    __shared__ float sl[36 * 128];  // staged input rows tt0-2 .. tt0+33 ; reused for cl[32][129]
    const int b = blockIdx.x >> 4;
    const int tt0 = (blockIdx.x & 15) * 32;
    const int co = threadIdx.x;
    for (int r = 0; r < 36; ++r) {
        int t = tt0 + r - 2;
        sl[r * 128 + co] = (t >= 0 && t < T_) ? snn[(size_t)(b * T_ + t) * 128 + co] : 0.f;
    }
    __syncthreads();
    float acc[32];
#pragma unroll
    for (int i = 0; i < 32; ++i) acc[i] = 0.f;
    for (int ci = 0; ci < 128; ++ci) {
        const float* wp = &Wc[(size_t)(co * 128 + ci) * 5];
        float w0 = wp[0], w1 = wp[1], w2 = wp[2], w3 = wp[3], w4 = wp[4];
        const float* col = &sl[ci];
        float r0 = col[0 * 128], r1 = col[1 * 128], r2 = col[2 * 128], r3 = col[3 * 128];
#pragma unroll
        for (int i = 0; i < 32; ++i) {
            float r4 = col[(i + 4) * 128];
            acc[i] += w0 * r0 + w1 * r1 + w2 * r2 + w3 * r3 + w4 * r4;
            r0 = r1; r1 = r2; r2 = r3; r3 = r4;
        }
    }
    float bco = bc[co];
    __syncthreads();  // everyone done reading sl
    float* cl = sl;   // [32][129]
#pragma unroll
    for (int i = 0; i < 32; ++i) cl[i * 129 + co] = acc[i] + bco;
    __syncthreads();
    if (co < 32) {
        int t = tt0 + co;
        float mx = -3.4e38f;
        for (int c = 0; c < 128; ++c) mx = fmaxf(mx, cl[co * 129 + c]);
        float se = 0.f;
        for (int c = 0; c < 128; ++c) se += expf(cl[co * 129 + c] - mx);
        float lse = mx + logf(se);
        for (int c = 0; c < 128; ++c)
            out0[((size_t)(b * 128 + c)) * T_ + t] = cl[co * 129 + c] - lse;
    }
}

// ---------------- launch ----------------
extern "C" void kernel_launch(void* const* d_in, const int* in_sizes, int n_in,
                              void* d_out, int out_size, void* d_ws, size_t ws_size,
                              hipStream_t stream) {
    (void)in_sizes; (void)n_in; (void)out_size; (void)ws_size;
    const float* x      = (const float*)d_in[0];   // [B,T,N]
    const float* sc     = (const float*)d_in[1];   // [N,N]
    const float* W_proj = (const float*)d_in[2];   // [N,H]
    const float* b_proj = (const float*)d_in[3];
    const float* ln_g   = (const float*)d_in[4];
    const float* ln_b   = (const float*)d_in[5];
    const float* W_enc  = (const float*)d_in[6];   // [H,N]
    const float* b_enc  = (const float*)d_in[7];
    const float* omega  = (const float*)d_in[8];   // [N,D]
    const float* W_mask = (const float*)d_in[9];   // [N,N]
    const float* b_mask = (const float*)d_in[10];
    const float* W_in   = (const float*)d_in[11];  // [N*D,H]
    const float* b_in   = (const float*)d_in[12];
    const float* W_out  = (const float*)d_in[13];  // [H,C]
    const float* b_out  = (const float*)d_in[14];
    const float* W_conv = (const float*)d_in[15];  // [C,C,5]
    const float* b_conv = (const float*)d_in[16];

    float* out0 = (float*)d_out;                   // [B,C,T] = 2,097,152 floats
    float* out1 = out0 + (size_t)B_ * C_ * T_;     // [B,T,H] = 33,554,432 floats (also Z / cur scratch)

    const int M = B_ * T_;  // 16384
    char* w = (char*)d_ws;
    unsigned* bar   = (unsigned*)w;                               // 256 B
    float* gamma    = (float*)(w + 256);                          // [M, N] 33.5 MB
    float* feat     = gamma + (size_t)M * N_;                     // [M, N*D] 134.2 MB
    unsigned* stct  = (unsigned*)(feat + (size_t)M * N_ * D_);    // [2][65536] 0.5 MB
    float* g_ring   = (float*)(stct + 2 * 65536);                 // [4][16384]
    float* mh_ring  = g_ring + 4 * (B_ * N_);                     // [4][16384]
    float* snn_pre  = gamma;                                      // reuse (gamma dead after scan)

    hipMemsetAsync(bar, 0, 256, stream);

    // G1: Z = x @ W_proj + b_proj   -> out1 (as Z scratch)
    gemm_f32<<<dim3(H_ / 128, M / 128), 256, 0, stream>>>(x, W_proj, b_proj, out1, M, H_, N_);
    // LN + LeakyReLU in place
    ln_leaky_kernel<<<M, 256, 0, stream>>>(out1, ln_g, ln_b);
    // G2: gamma = Z @ W_enc + b_enc
    gemm_f32<<<dim3(N_ / 128, M / 128), 256, 0, stream>>>(out1, W_enc, b_enc, gamma, M, N_, H_);
    // persistent theta scan -> feat
    scan_kernel<<<256, 256, SCAN_LDS_BYTES, stream>>>(sc, gamma, omega, W_mask, b_mask,
                                                      feat, stct, g_ring, mh_ring, bar);
    // G3: cur = feat @ W_in + b_in  -> out1 (overwrites Z)
    gemm_f32<<<dim3(H_ / 128, M / 128), 256, 0, stream>>>(feat, W_in, b_in, out1, M, H_, N_ * D_);
    // LIF membrane scan: cur -> spikes in place (final output 1)
    mem_scan_kernel<<<256, 256, 0, stream>>>(out1);
    // G4: snn_pre = spikes @ W_out + b_out
    gemm_f32<<<dim3(C_ / 128, M / 128), 256, 0, stream>>>(out1, W_out, b_out, snn_pre, M, C_, H_);
    // conv1d + log_softmax -> out0
    conv_lsm_kernel<<<dim3(B_ * 16), 128, 0, stream>>>(snn_pre, W_conv, b_conv, out0);
}